// Round 10
// baseline (765.007 us; speedup 1.0000x reference)
//
#include <hip/hip_runtime.h>
#include <hip/hip_fp16.h>
#include <math.h>

#define TAU 0.5f   // |pivot|^2 threshold (f32) for the fast pivot path

// ---------------------------------------------------------------------------
// Fused kernel: 2304 blocks x 256 threads (9 blocks/CU exactly).
//   bid < 256  -> conv block (conv-first). bid 0,1 FALL THROUGH into logdet
//                 with key 2048+bid (straight-line; loop-wrapping spills).
//   bid >= 256 -> logdet block, key = bid-256 (0..2047).
//
// r25 delta: software-pipelined prefix. r24 post-mortem: VALUBusy stuck at
//   ~61% with a pure-VALU stream at full residency -> the stall is the
//   serial prefix chain (ballot->ffs->readlane x2->rcp->cvt, ~200-400cy)
//   at the TOP of each k-step with nothing independent in front of it.
//   New iteration order: CHUNK(0) -> PREFIX(k+1) (from new a2[0]) ->
//   CHUNK(1..C-1) (old coefs, independent of prefix) -> rotate.
//   Arithmetic bit-identical; coefs loop-carried (+~4 VGPR). The 64th
//   prefix (last iteration) reproduces the old last-lane pivmag epilogue
//   exactly (incl. NaN fallback), so the epilogue latch is dropped.
// r24 established: staged static-chunk staircase (no per-k guards),
//   cndmask-free self-eliminating retired rows, readlane(mag) for magp.
// Ledger: r8/r13/r14 DS broadcasts + SALU swaps regress; r16-r18 LDS
// column staging spills/neutral; r21 b128 marshalling spills; r22 runtime
// rep-loop around body spills. Straight-line body + static indices only.
// ---------------------------------------------------------------------------
__device__ __forceinline__ int h2i(__half2 h) { int i; __builtin_memcpy(&i, &h, 4); return i; }
__device__ __forceinline__ __half2 i2h(int i) { __half2 h; __builtin_memcpy(&h, &i, 4); return h; }

#define UPD(SL, LV) {                                                     \
    __half2 P_ = i2h(LV);                                                 \
    __half2 t_ = __hfma2(nfre2, P_, a2[SL]);                              \
    a2[(SL) - 1] = __hfma2(fim2, __lowhigh2highlow(P_), t_); }

#define CHUNK(CH) {                                                       \
    int l0 = __builtin_amdgcn_readlane(h2i(a2[(CH) * 8 + 1]), p);         \
    int l1 = __builtin_amdgcn_readlane(h2i(a2[(CH) * 8 + 2]), p);         \
    int l2 = __builtin_amdgcn_readlane(h2i(a2[(CH) * 8 + 3]), p);         \
    int l3 = __builtin_amdgcn_readlane(h2i(a2[(CH) * 8 + 4]), p);         \
    int l4 = __builtin_amdgcn_readlane(h2i(a2[(CH) * 8 + 5]), p);         \
    int l5 = __builtin_amdgcn_readlane(h2i(a2[(CH) * 8 + 6]), p);         \
    int l6 = __builtin_amdgcn_readlane(h2i(a2[(CH) * 8 + 7]), p);         \
    int l7 = __builtin_amdgcn_readlane(h2i(a2[(CH) * 8 + 8]), p);         \
    UPD((CH) * 8 + 1, l0) UPD((CH) * 8 + 2, l1) UPD((CH) * 8 + 3, l2)     \
    UPD((CH) * 8 + 4, l3) UPD((CH) * 8 + 5, l4) UPD((CH) * 8 + 6, l5)     \
    UPD((CH) * 8 + 7, l6) UPD((CH) * 8 + 8, l7) }

// Computes step-(k+1) pivot/coefs from the CURRENT a2[0]; latches pivmag,
// updates active, writes (pn, nfre2n, fim2n). Executed 64x total; the 64th
// performs the final-lane pivmag latch (= old epilogue).
#define PREFIX_CORE() {                                                   \
    float fr0 = __low2float(a2[0]);                                       \
    float fi0 = __high2float(a2[0]);                                      \
    float mag = fmaf(fr0, fr0, fi0 * fi0);                                \
    unsigned long long candm = __ballot(active && (mag >= TAU));          \
    int p_;                                                               \
    if (candm != 0ULL) {                                                  \
      p_ = __ffsll(candm) - 1;                                            \
    } else {                                                              \
      float mm = active ? mag : -1.0f;                                    \
      for (int off = 32; off > 0; off >>= 1)                              \
        mm = fmaxf(mm, __shfl_xor(mm, off));                              \
      unsigned long long mx = __ballot(active && (mag == mm));            \
      if (mx == 0ULL) mx = __ballot(active);                              \
      p_ = __ffsll(mx) - 1;                                               \
    }                                                                     \
    p_ &= 63;                                                             \
    bool isPiv = (r == p_);                                               \
    pivmag = isPiv ? mag : pivmag;                                        \
    active = active && !isPiv;                                            \
    float magp = __int_as_float(                                          \
        __builtin_amdgcn_readlane(__float_as_int(mag), p_));              \
    __half2 pivh = i2h(__builtin_amdgcn_readlane(h2i(a2[0]), p_));        \
    float pr = __low2float(pivh);                                         \
    float pi = __high2float(pivh);                                        \
    float inv = __builtin_amdgcn_rcpf(magp);                              \
    float fre = (fr0 * pr + fi0 * pi) * inv;                              \
    float fim = (fi0 * pr - fr0 * pi) * inv;                              \
    pn = p_;                                                              \
    nfre2n = __float2half2_rn(-fre);                                      \
    fim2n = __halves2half2(__float2half_rn(fim), __float2half_rn(-fim)); }

#define ROTATE() { p = pn; nfre2 = nfre2n; fim2 = fim2n; }

__global__ __launch_bounds__(256, 3) void fused_kernel(
    const float* __restrict__ x, const float* __restrict__ K,
    const float* __restrict__ bias, float* __restrict__ out,
    float* __restrict__ logdet) {
  __shared__ float smem[4928];               // conv: w[576] + tile[64*68]
  int bid = blockIdx.x;
  int t = threadIdx.x;

  int key;                                   // logdet key (phi: two sources)
  if (bid < 256) {
    // ================= conv =================
    int b = bid >> 6, co = bid & 63;
    float* w = smem;                         // 576
    float* tile = smem + 576;                // 64*68 (stride 68: 16B-aligned)

    for (int i = t; i < 576; i += 256) {
      float vv = K[(size_t)((b * 64 + co) * 64) * 9 + i];
      if (i == co * 9 + 4) vv += 1.0f;       // identity: ci==co, center tap
      w[i] = vv;
    }

    int ty = t >> 2;
    int tx = t & 3;
    int x0 = tx << 4;
    float bval = bias[b * 64 + co];
    float acc[16];
#pragma unroll
    for (int i = 0; i < 16; ++i) acc[i] = bval;

    const float* xb = x + (size_t)(b * 64) * 4096;
    for (int ci = 0; ci < 64; ++ci) {
      __syncthreads();                       // WAR on tile (and w on first iter)
      const float4* xc4 = (const float4*)(xb + (size_t)ci * 4096);
#pragma unroll
      for (int j = 0; j < 4; ++j) {          // 4x (dwordx4 load + b128 LDS write)
        int i4 = t + 256 * j;                // float4 index 0..1023
        int row = i4 >> 4;                   // 16 float4 per 64-wide row
        int col = (i4 & 15) << 2;
        float4 vv = xc4[i4];
        *(float4*)&tile[row * 68 + col] = vv;
      }
      __syncthreads();

      float w0 = w[ci * 9 + 0], w1 = w[ci * 9 + 1], w2 = w[ci * 9 + 2];
      float w3 = w[ci * 9 + 3], w4 = w[ci * 9 + 4], w5 = w[ci * 9 + 5];
      float w6 = w[ci * 9 + 6], w7 = w[ci * 9 + 7], w8 = w[ci * 9 + 8];

      int ym = ((ty - 1) & 63) * 68;
      int yc = ty * 68;
      int yp = ((ty + 1) & 63) * 68;
      float in0[18], in1[18], in2[18];
#pragma unroll
      for (int q = 0; q < 4; ++q) {          // interior: 12x ds_read_b128
        float4 v0 = *(const float4*)&tile[ym + x0 + 4 * q];
        float4 v1 = *(const float4*)&tile[yc + x0 + 4 * q];
        float4 v2 = *(const float4*)&tile[yp + x0 + 4 * q];
        in0[1 + 4 * q] = v0.x; in0[2 + 4 * q] = v0.y; in0[3 + 4 * q] = v0.z; in0[4 + 4 * q] = v0.w;
        in1[1 + 4 * q] = v1.x; in1[2 + 4 * q] = v1.y; in1[3 + 4 * q] = v1.z; in1[4 + 4 * q] = v1.w;
        in2[1 + 4 * q] = v2.x; in2[2 + 4 * q] = v2.y; in2[3 + 4 * q] = v2.z; in2[4 + 4 * q] = v2.w;
      }
      in0[0]  = tile[ym + ((x0 - 1) & 63)];  // 6 scalar edge reads (wrap)
      in0[17] = tile[ym + ((x0 + 16) & 63)];
      in1[0]  = tile[yc + ((x0 - 1) & 63)];
      in1[17] = tile[yc + ((x0 + 16) & 63)];
      in2[0]  = tile[yp + ((x0 - 1) & 63)];
      in2[17] = tile[yp + ((x0 + 16) & 63)];
#pragma unroll
      for (int px = 0; px < 16; ++px) {
        float a = acc[px];
        a = fmaf(w0, in0[px], a); a = fmaf(w1, in0[px + 1], a); a = fmaf(w2, in0[px + 2], a);
        a = fmaf(w3, in1[px], a); a = fmaf(w4, in1[px + 1], a); a = fmaf(w5, in1[px + 2], a);
        a = fmaf(w6, in2[px], a); a = fmaf(w7, in2[px + 1], a); a = fmaf(w8, in2[px + 2], a);
        acc[px] = a;
      }
    }

    float* op = out + (size_t)(b * 64 + co) * 4096 + ty * 64 + x0;
#pragma unroll
    for (int i = 0; i < 16; i += 4) {
      *(float4*)(op + i) = make_float4(acc[i], acc[i + 1], acc[i + 2], acc[i + 3]);
    }

    if (bid >= 2) return;                    // blocks 0,1 continue to logdet
    key = 2048 + bid;                        // keys 2048, 2049
  } else {
    key = bid - 256;                         // 0..2047
  }

  // ================= logdet (straight-line, single entry) =================
  int b = t >> 6;                            // wave id == batch
  int r = t & 63;                            // lane == matrix row

  int u, v;
  if (key < 33) { u = 0; v = key; }
  else if (key < 2017) { int q = key - 33; u = 1 + (q >> 6); v = q & 63; }
  else { u = 32; v = key - 2017; }
  float weight = (((u & 31) == 0) && ((v & 31) == 0)) ? 1.0f : 2.0f;

  // twiddles w[kh*3+kw] = e^{-2*pi*i*(u*kh+v*kw)/64} via complex power products
  float Ar[3], Ai[3], Br[3], Bi[3];
  {
    const float k2pi = -6.283185307179586f / 64.0f;
    float su, cu, sv, cv;
    __sincosf(k2pi * (float)u, &su, &cu);
    __sincosf(k2pi * (float)v, &sv, &cv);
    Ar[0] = 1.0f; Ai[0] = 0.0f; Ar[1] = cu; Ai[1] = su;
    Ar[2] = cu * cu - su * su; Ai[2] = 2.0f * cu * su;
    Br[0] = 1.0f; Bi[0] = 0.0f; Br[1] = cv; Bi[1] = sv;
    Br[2] = cv * cv - sv * sv; Bi[2] = 2.0f * cv * sv;
  }
  float wr[9], wi[9];
#pragma unroll
  for (int kh = 0; kh < 3; ++kh)
#pragma unroll
    for (int kw = 0; kw < 3; ++kw) {
      wr[kh * 3 + kw] = Ar[kh] * Br[kw] - Ai[kh] * Bi[kw];
      wi[kh * 3 + kw] = Ar[kh] * Bi[kw] + Ai[kh] * Br[kw];
    }

  // Build row r of Khat in fp32, pack each column to f16x2 immediately.
  __half2 a2[65];
  const float4* Kp4 = (const float4*)(K + (size_t)(b * 64 + r) * 576);
#pragma unroll
  for (int g = 0; g < 16; ++g) {             // 16 groups x 4 columns
    float f[36];
#pragma unroll
    for (int qq = 0; qq < 9; ++qq) {
      float4 vv = Kp4[g * 9 + qq];
      f[qq * 4 + 0] = vv.x; f[qq * 4 + 1] = vv.y; f[qq * 4 + 2] = vv.z; f[qq * 4 + 3] = vv.w;
    }
#pragma unroll
    for (int cc = 0; cc < 4; ++cc) {
      int c = g * 4 + cc;
      float re = 0.0f, im = 0.0f;
#pragma unroll
      for (int t9 = 0; t9 < 9; ++t9) {
        float kv = f[cc * 9 + t9];
        re = fmaf(kv, wr[t9], re);
        im = fmaf(kv, wi[t9], im);
      }
      if (c == r) { re += wr[4]; im += wi[4]; }  // identity: center-tap delta
      a2[c] = __floats2half2_rn(re, im);
    }
  }
  a2[64] = __floats2half2_rn(0.0f, 0.0f);    // pad slot for chunk overshoot

  bool active = true;
  float pivmag = 1.0f;                       // each lane's own pivot |.|^2 (f32)
  int p, pn;
  __half2 nfre2, fim2, nfre2n, fim2n;

  PREFIX_CORE()                              // step-0 pivot/coefs
  ROTATE()

  // Pipelined staged elimination: per k-iteration:
  //   CHUNK(0) -> PREFIX(k+1) -> CHUNK(1..C-1) -> rotate.
#pragma unroll 1
  for (int k = 0; k < 7; ++k) {              // rem 63..57, C=8
    CHUNK(0)
    PREFIX_CORE()
    CHUNK(1) CHUNK(2) CHUNK(3) CHUNK(4) CHUNK(5) CHUNK(6) CHUNK(7)
    ROTATE()
  }
#pragma unroll 1
  for (int k = 0; k < 8; ++k) {              // rem 56..49, C=7
    CHUNK(0)
    PREFIX_CORE()
    CHUNK(1) CHUNK(2) CHUNK(3) CHUNK(4) CHUNK(5) CHUNK(6)
    ROTATE()
  }
#pragma unroll 1
  for (int k = 0; k < 8; ++k) {              // rem 48..41, C=6
    CHUNK(0)
    PREFIX_CORE()
    CHUNK(1) CHUNK(2) CHUNK(3) CHUNK(4) CHUNK(5)
    ROTATE()
  }
#pragma unroll 1
  for (int k = 0; k < 8; ++k) {              // rem 40..33, C=5
    CHUNK(0)
    PREFIX_CORE()
    CHUNK(1) CHUNK(2) CHUNK(3) CHUNK(4)
    ROTATE()
  }
#pragma unroll 1
  for (int k = 0; k < 8; ++k) {              // rem 32..25, C=4
    CHUNK(0)
    PREFIX_CORE()
    CHUNK(1) CHUNK(2) CHUNK(3)
    ROTATE()
  }
#pragma unroll 1
  for (int k = 0; k < 8; ++k) {              // rem 24..17, C=3
    CHUNK(0)
    PREFIX_CORE()
    CHUNK(1) CHUNK(2)
    ROTATE()
  }
#pragma unroll 1
  for (int k = 0; k < 8; ++k) {              // rem 16..9, C=2
    CHUNK(0)
    PREFIX_CORE()
    CHUNK(1)
    ROTATE()
  }
#pragma unroll 1
  for (int k = 0; k < 8; ++k) {              // rem 8..1, C=1
    CHUNK(0)
    PREFIX_CORE()                            // 64th latches last-lane pivmag
    ROTATE()
  }

  float logsum = 0.5f * __logf(pivmag);      // one log per lane; sum = logdet
#pragma unroll
  for (int off = 32; off > 0; off >>= 1) logsum += __shfl_xor(logsum, off);
  if (r == 0) atomicAdd(&logdet[b], weight * logsum);
}

// ---------------------------------------------------------------------------
extern "C" void kernel_launch(void* const* d_in, const int* in_sizes, int n_in,
                              void* d_out, int out_size, void* d_ws, size_t ws_size,
                              hipStream_t stream) {
  const float* conv_in = (const float*)d_in[0];   // [4,64,64,64]
  const float* K       = (const float*)d_in[1];   // [4,64,64,3,3]
  const float* bias    = (const float*)d_in[2];   // [4,64,1,1]
  float* out = (float*)d_out;                     // conv_out (1048576) ++ logdet (4)
  float* logdet = out + 1048576;

  hipMemsetAsync(logdet, 0, 4 * sizeof(float), stream);
  fused_kernel<<<dim3(2304), dim3(256), 0, stream>>>(conv_in, K, bias, out, logdet);
}

// Round 11
// 298.095 us; speedup vs baseline: 2.5663x; 2.5663x over previous
//
#include <hip/hip_runtime.h>
#include <hip/hip_fp16.h>
#include <math.h>

#define TAU 0.5f   // |pivot|^2 threshold (f32) for the fast pivot path

// ---------------------------------------------------------------------------
// Fused kernel: 2304 blocks x 256 threads (9 blocks/CU exactly).
//   bid < 256  -> conv block (conv-first). bid 0,1 FALL THROUGH into logdet
//                 with key 2048+bid (straight-line; loop-wrapping spills).
//   bid >= 256 -> logdet block, key = bid-256 (0..2047).
//
// r26 = r24 (best clean: 285us dispatch) + magp recomputed from pivh
//   (bit-identical: pr,pi = the same fp16 values mag was computed from at
//   lane p) -- removes 63 crossbar readlanes/wave.
// r25 post-mortem: pipelined prefix with loop-carried coef sets spilled
//   (3rd restructuring spill: r21, r22, r25). RULE: no live state may be
//   added across the k-loop back-edge beyond {active, pivmag, a2}.
// Standing theory: lane-crossbar saturation caps VALUBusy at ~61%
//   (~25% of stream is cross-lane; 7 resident waves/SIMD can't cover a
//   shared-unit stall). Only op-count cuts move dur (r24: -15us).
// Ledger: r8/r13/r14 DS broadcasts + SALU swaps regress; r16-r18 LDS
// column staging spills/neutral; r21 b128 marshalling spills; r22/r25
// loop-carried restructures spill. Straight-line + static indices only.
// ---------------------------------------------------------------------------
__device__ __forceinline__ int h2i(__half2 h) { int i; __builtin_memcpy(&i, &h, 4); return i; }
__device__ __forceinline__ __half2 i2h(int i) { __half2 h; __builtin_memcpy(&h, &i, 4); return h; }

#define UPD(SL, LV) {                                                     \
    __half2 P_ = i2h(LV);                                                 \
    __half2 t_ = __hfma2(nfre2, P_, a2[SL]);                              \
    a2[(SL) - 1] = __hfma2(fim2, __lowhigh2highlow(P_), t_); }

#define CHUNK(CH) {                                                       \
    int l0 = __builtin_amdgcn_readlane(h2i(a2[(CH) * 8 + 1]), p);         \
    int l1 = __builtin_amdgcn_readlane(h2i(a2[(CH) * 8 + 2]), p);         \
    int l2 = __builtin_amdgcn_readlane(h2i(a2[(CH) * 8 + 3]), p);         \
    int l3 = __builtin_amdgcn_readlane(h2i(a2[(CH) * 8 + 4]), p);         \
    int l4 = __builtin_amdgcn_readlane(h2i(a2[(CH) * 8 + 5]), p);         \
    int l5 = __builtin_amdgcn_readlane(h2i(a2[(CH) * 8 + 6]), p);         \
    int l6 = __builtin_amdgcn_readlane(h2i(a2[(CH) * 8 + 7]), p);         \
    int l7 = __builtin_amdgcn_readlane(h2i(a2[(CH) * 8 + 8]), p);         \
    UPD((CH) * 8 + 1, l0) UPD((CH) * 8 + 2, l1) UPD((CH) * 8 + 3, l2)     \
    UPD((CH) * 8 + 4, l3) UPD((CH) * 8 + 5, l4) UPD((CH) * 8 + 6, l5)     \
    UPD((CH) * 8 + 7, l6) UPD((CH) * 8 + 8, l7) }

#define PREFIX()                                                          \
    float fr0 = __low2float(a2[0]);                                       \
    float fi0 = __high2float(a2[0]);                                      \
    float mag = fmaf(fr0, fr0, fi0 * fi0);                                \
    unsigned long long candm = __ballot(active && (mag >= TAU));          \
    int p;                                                                \
    if (candm != 0ULL) {                                                  \
      p = __ffsll(candm) - 1;                                             \
    } else {                                                              \
      float mm = active ? mag : -1.0f;                                    \
      for (int off = 32; off > 0; off >>= 1)                              \
        mm = fmaxf(mm, __shfl_xor(mm, off));                              \
      unsigned long long mx = __ballot(active && (mag == mm));            \
      if (mx == 0ULL) mx = __ballot(active);                              \
      p = __ffsll(mx) - 1;                                                \
    }                                                                     \
    p &= 63;                                                              \
    bool isPiv = (r == p);                                                \
    pivmag = isPiv ? mag : pivmag;                                        \
    active = active && !isPiv;                                            \
    __half2 pivh = i2h(__builtin_amdgcn_readlane(h2i(a2[0]), p));         \
    float pr = __low2float(pivh);                                         \
    float pi = __high2float(pivh);                                        \
    float inv = __builtin_amdgcn_rcpf(fmaf(pr, pr, pi * pi));             \
    float fre = (fr0 * pr + fi0 * pi) * inv;                              \
    float fim = (fi0 * pr - fr0 * pi) * inv;                              \
    __half2 nfre2 = __float2half2_rn(-fre);                               \
    __half2 fim2 = __halves2half2(__float2half_rn(fim),                   \
                                  __float2half_rn(-fim));

__global__ __launch_bounds__(256, 3) void fused_kernel(
    const float* __restrict__ x, const float* __restrict__ K,
    const float* __restrict__ bias, float* __restrict__ out,
    float* __restrict__ logdet) {
  __shared__ float smem[4928];               // conv: w[576] + tile[64*68]
  int bid = blockIdx.x;
  int t = threadIdx.x;

  int key;                                   // logdet key (phi: two sources)
  if (bid < 256) {
    // ================= conv =================
    int b = bid >> 6, co = bid & 63;
    float* w = smem;                         // 576
    float* tile = smem + 576;                // 64*68 (stride 68: 16B-aligned)

    for (int i = t; i < 576; i += 256) {
      float vv = K[(size_t)((b * 64 + co) * 64) * 9 + i];
      if (i == co * 9 + 4) vv += 1.0f;       // identity: ci==co, center tap
      w[i] = vv;
    }

    int ty = t >> 2;
    int tx = t & 3;
    int x0 = tx << 4;
    float bval = bias[b * 64 + co];
    float acc[16];
#pragma unroll
    for (int i = 0; i < 16; ++i) acc[i] = bval;

    const float* xb = x + (size_t)(b * 64) * 4096;
    for (int ci = 0; ci < 64; ++ci) {
      __syncthreads();                       // WAR on tile (and w on first iter)
      const float4* xc4 = (const float4*)(xb + (size_t)ci * 4096);
#pragma unroll
      for (int j = 0; j < 4; ++j) {          // 4x (dwordx4 load + b128 LDS write)
        int i4 = t + 256 * j;                // float4 index 0..1023
        int row = i4 >> 4;                   // 16 float4 per 64-wide row
        int col = (i4 & 15) << 2;
        float4 vv = xc4[i4];
        *(float4*)&tile[row * 68 + col] = vv;
      }
      __syncthreads();

      float w0 = w[ci * 9 + 0], w1 = w[ci * 9 + 1], w2 = w[ci * 9 + 2];
      float w3 = w[ci * 9 + 3], w4 = w[ci * 9 + 4], w5 = w[ci * 9 + 5];
      float w6 = w[ci * 9 + 6], w7 = w[ci * 9 + 7], w8 = w[ci * 9 + 8];

      int ym = ((ty - 1) & 63) * 68;
      int yc = ty * 68;
      int yp = ((ty + 1) & 63) * 68;
      float in0[18], in1[18], in2[18];
#pragma unroll
      for (int q = 0; q < 4; ++q) {          // interior: 12x ds_read_b128
        float4 v0 = *(const float4*)&tile[ym + x0 + 4 * q];
        float4 v1 = *(const float4*)&tile[yc + x0 + 4 * q];
        float4 v2 = *(const float4*)&tile[yp + x0 + 4 * q];
        in0[1 + 4 * q] = v0.x; in0[2 + 4 * q] = v0.y; in0[3 + 4 * q] = v0.z; in0[4 + 4 * q] = v0.w;
        in1[1 + 4 * q] = v1.x; in1[2 + 4 * q] = v1.y; in1[3 + 4 * q] = v1.z; in1[4 + 4 * q] = v1.w;
        in2[1 + 4 * q] = v2.x; in2[2 + 4 * q] = v2.y; in2[3 + 4 * q] = v2.z; in2[4 + 4 * q] = v2.w;
      }
      in0[0]  = tile[ym + ((x0 - 1) & 63)];  // 6 scalar edge reads (wrap)
      in0[17] = tile[ym + ((x0 + 16) & 63)];
      in1[0]  = tile[yc + ((x0 - 1) & 63)];
      in1[17] = tile[yc + ((x0 + 16) & 63)];
      in2[0]  = tile[yp + ((x0 - 1) & 63)];
      in2[17] = tile[yp + ((x0 + 16) & 63)];
#pragma unroll
      for (int px = 0; px < 16; ++px) {
        float a = acc[px];
        a = fmaf(w0, in0[px], a); a = fmaf(w1, in0[px + 1], a); a = fmaf(w2, in0[px + 2], a);
        a = fmaf(w3, in1[px], a); a = fmaf(w4, in1[px + 1], a); a = fmaf(w5, in1[px + 2], a);
        a = fmaf(w6, in2[px], a); a = fmaf(w7, in2[px + 1], a); a = fmaf(w8, in2[px + 2], a);
        acc[px] = a;
      }
    }

    float* op = out + (size_t)(b * 64 + co) * 4096 + ty * 64 + x0;
#pragma unroll
    for (int i = 0; i < 16; i += 4) {
      *(float4*)(op + i) = make_float4(acc[i], acc[i + 1], acc[i + 2], acc[i + 3]);
    }

    if (bid >= 2) return;                    // blocks 0,1 continue to logdet
    key = 2048 + bid;                        // keys 2048, 2049
  } else {
    key = bid - 256;                         // 0..2047
  }

  // ================= logdet (straight-line, single entry) =================
  int b = t >> 6;                            // wave id == batch
  int r = t & 63;                            // lane == matrix row

  int u, v;
  if (key < 33) { u = 0; v = key; }
  else if (key < 2017) { int q = key - 33; u = 1 + (q >> 6); v = q & 63; }
  else { u = 32; v = key - 2017; }
  float weight = (((u & 31) == 0) && ((v & 31) == 0)) ? 1.0f : 2.0f;

  // twiddles w[kh*3+kw] = e^{-2*pi*i*(u*kh+v*kw)/64} via complex power products
  float Ar[3], Ai[3], Br[3], Bi[3];
  {
    const float k2pi = -6.283185307179586f / 64.0f;
    float su, cu, sv, cv;
    __sincosf(k2pi * (float)u, &su, &cu);
    __sincosf(k2pi * (float)v, &sv, &cv);
    Ar[0] = 1.0f; Ai[0] = 0.0f; Ar[1] = cu; Ai[1] = su;
    Ar[2] = cu * cu - su * su; Ai[2] = 2.0f * cu * su;
    Br[0] = 1.0f; Bi[0] = 0.0f; Br[1] = cv; Bi[1] = sv;
    Br[2] = cv * cv - sv * sv; Bi[2] = 2.0f * cv * sv;
  }
  float wr[9], wi[9];
#pragma unroll
  for (int kh = 0; kh < 3; ++kh)
#pragma unroll
    for (int kw = 0; kw < 3; ++kw) {
      wr[kh * 3 + kw] = Ar[kh] * Br[kw] - Ai[kh] * Bi[kw];
      wi[kh * 3 + kw] = Ar[kh] * Bi[kw] + Ai[kh] * Br[kw];
    }

  // Build row r of Khat in fp32, pack each column to f16x2 immediately.
  __half2 a2[65];
  const float4* Kp4 = (const float4*)(K + (size_t)(b * 64 + r) * 576);
#pragma unroll
  for (int g = 0; g < 16; ++g) {             // 16 groups x 4 columns
    float f[36];
#pragma unroll
    for (int qq = 0; qq < 9; ++qq) {
      float4 vv = Kp4[g * 9 + qq];
      f[qq * 4 + 0] = vv.x; f[qq * 4 + 1] = vv.y; f[qq * 4 + 2] = vv.z; f[qq * 4 + 3] = vv.w;
    }
#pragma unroll
    for (int cc = 0; cc < 4; ++cc) {
      int c = g * 4 + cc;
      float re = 0.0f, im = 0.0f;
#pragma unroll
      for (int t9 = 0; t9 < 9; ++t9) {
        float kv = f[cc * 9 + t9];
        re = fmaf(kv, wr[t9], re);
        im = fmaf(kv, wi[t9], im);
      }
      if (c == r) { re += wr[4]; im += wi[4]; }  // identity: center-tap delta
      a2[c] = __floats2half2_rn(re, im);
    }
  }
  a2[64] = __floats2half2_rn(0.0f, 0.0f);    // pad slot for chunk overshoot

  bool active = true;
  float pivmag = 1.0f;                       // each lane's own pivot |.|^2 (f32)

  // Staged elimination: 63 steps, chunk count = ceil(rem/8) staircase.
#pragma unroll 1
  for (int k = 0; k < 7; ++k) {              // rem 63..57
    PREFIX()
    CHUNK(0) CHUNK(1) CHUNK(2) CHUNK(3) CHUNK(4) CHUNK(5) CHUNK(6) CHUNK(7)
  }
#pragma unroll 1
  for (int k = 0; k < 8; ++k) {              // rem 56..49
    PREFIX()
    CHUNK(0) CHUNK(1) CHUNK(2) CHUNK(3) CHUNK(4) CHUNK(5) CHUNK(6)
  }
#pragma unroll 1
  for (int k = 0; k < 8; ++k) {              // rem 48..41
    PREFIX()
    CHUNK(0) CHUNK(1) CHUNK(2) CHUNK(3) CHUNK(4) CHUNK(5)
  }
#pragma unroll 1
  for (int k = 0; k < 8; ++k) {              // rem 40..33
    PREFIX()
    CHUNK(0) CHUNK(1) CHUNK(2) CHUNK(3) CHUNK(4)
  }
#pragma unroll 1
  for (int k = 0; k < 8; ++k) {              // rem 32..25
    PREFIX()
    CHUNK(0) CHUNK(1) CHUNK(2) CHUNK(3)
  }
#pragma unroll 1
  for (int k = 0; k < 8; ++k) {              // rem 24..17
    PREFIX()
    CHUNK(0) CHUNK(1) CHUNK(2)
  }
#pragma unroll 1
  for (int k = 0; k < 8; ++k) {              // rem 16..9
    PREFIX()
    CHUNK(0) CHUNK(1)
  }
#pragma unroll 1
  for (int k = 0; k < 8; ++k) {              // rem 8..1
    PREFIX()
    CHUNK(0)
  }

  {
    float fr0 = __low2float(a2[0]);
    float fi0 = __high2float(a2[0]);
    if (active) pivmag = fmaf(fr0, fr0, fi0 * fi0);  // last surviving row
  }

  float logsum = 0.5f * __logf(pivmag);      // one log per lane; sum = logdet
#pragma unroll
  for (int off = 32; off > 0; off >>= 1) logsum += __shfl_xor(logsum, off);
  if (r == 0) atomicAdd(&logdet[b], weight * logsum);
}

// ---------------------------------------------------------------------------
extern "C" void kernel_launch(void* const* d_in, const int* in_sizes, int n_in,
                              void* d_out, int out_size, void* d_ws, size_t ws_size,
                              hipStream_t stream) {
  const float* conv_in = (const float*)d_in[0];   // [4,64,64,64]
  const float* K       = (const float*)d_in[1];   // [4,64,64,3,3]
  const float* bias    = (const float*)d_in[2];   // [4,64,1,1]
  float* out = (float*)d_out;                     // conv_out (1048576) ++ logdet (4)
  float* logdet = out + 1048576;

  hipMemsetAsync(logdet, 0, 4 * sizeof(float), stream);
  fused_kernel<<<dim3(2304), dim3(256), 0, stream>>>(conv_in, K, bias, out, logdet);
}